// Round 3
// baseline (930.944 us; speedup 1.0000x reference)
//
#include <hip/hip_runtime.h>
#include <hip/hip_bf16.h>

// CorotationalBeam2D: per-element 2D corotational beam forces + nodal scatter.
//
// Outputs (flat, concatenated in reference return order):
//   [0]       nodal_forces_nd : (N,3)
//   [3N]      F_ext_nd        : (N,3)
//   [6N]      N_e, [6N+E] M1_e, [6N+2E] M2_e, [6N+3E] V_e : (E,) each
//   [6N+4E]   phys_disp       : (N,3)
//   [9N+4E]   l0, [9N+5E] c, [9N+6E] s : (E,) each
//
// R1 diagnosis: elem kernel latency-bound (VALUBusy 1.6%, HBM 19%, occ 83%).
// R2 fix of R1 compile error: __builtin_nontemporal_* needs native clang
// vectors, not HIP_vector_type -> use ext_vector_type typedefs.

typedef float f32x4 __attribute__((ext_vector_type(4)));
typedef int   i32x4 __attribute__((ext_vector_type(4)));

__device__ __forceinline__ void atomic_add_f32(float* p, float v) {
#if defined(__gfx90a__) || defined(__gfx940__) || defined(__gfx941__) || defined(__gfx942__) || defined(__gfx950__)
    unsafeAtomicAdd(p, v);   // hardware global_atomic_add_f32
#else
    atomicAdd(p, v);
#endif
}

// Kernel 1: node-wise. phys_disp, F_ext_nd, and zero the nodal accumulator.
__global__ void __launch_bounds__(256) beam_node_kernel(
        const float* __restrict__ pred,
        const float* __restrict__ Fext,
        const float* __restrict__ u_c_p,
        const float* __restrict__ theta_c_p,
        const float* __restrict__ F_c_p,
        const float* __restrict__ M_c_p,
        float* __restrict__ nodal,
        float* __restrict__ Fext_nd,
        float* __restrict__ phys,
        int n3) {
    const float u_c = *u_c_p;
    const float theta_c = *theta_c_p;
    const float F_c = *F_c_p;
    const float M_c = *M_c_p;

    long t = (long)blockIdx.x * blockDim.x + threadIdx.x;
    long base = t * 4;
    if (base + 4 <= n3) {
        f32x4 p = __builtin_nontemporal_load((const f32x4*)(pred + base));
        f32x4 f = __builtin_nontemporal_load((const f32x4*)(Fext + base));
        f32x4 ph, fo;
        #pragma unroll
        for (int k = 0; k < 4; ++k) {
            int comp = (int)((base + k) % 3);
            float dscale = (comp == 2) ? theta_c : u_c;
            float fscale = (comp == 2) ? M_c : F_c;
            ph[k] = p[k] * dscale;
            fo[k] = f[k] / fscale;
        }
        f32x4 zz = (f32x4)0.0f;
        __builtin_nontemporal_store(ph, (f32x4*)(phys + base));
        __builtin_nontemporal_store(fo, (f32x4*)(Fext_nd + base));
        *(f32x4*)(nodal + base) = zz;   // atomics will hit these lines: keep cached
    } else {
        for (long i = base; i < n3; ++i) {
            int comp = (int)(i % 3);
            float dscale = (comp == 2) ? theta_c : u_c;
            float fscale = (comp == 2) ? M_c : F_c;
            phys[i] = pred[i] * dscale;
            Fext_nd[i] = Fext[i] / fscale;
            nodal[i] = 0.0f;
        }
    }
}

// Kernel 2: element-wise, 4 elements per thread.
__global__ void __launch_bounds__(256) beam_elem_kernel(
        const float* __restrict__ pred,
        const float* __restrict__ coords,
        const int*   __restrict__ conn,
        const float* __restrict__ prop_E,
        const float* __restrict__ prop_A,
        const float* __restrict__ prop_I,
        const float* __restrict__ u_c_p,
        const float* __restrict__ theta_c_p,
        const float* __restrict__ F_c_p,
        const float* __restrict__ M_c_p,
        float* __restrict__ nodal,
        float* __restrict__ N_e,
        float* __restrict__ M1_e,
        float* __restrict__ M2_e,
        float* __restrict__ V_e,
        float* __restrict__ l0_o,
        float* __restrict__ c_o,
        float* __restrict__ s_o,
        int n_elems) {
    const float u_c = *u_c_p;
    const float theta_c = *theta_c_p;
    const float F_c = *F_c_p;
    const float M_c = *M_c_p;

    long t = (long)blockIdx.x * blockDim.x + threadIdx.x;
    long base = t * 4;
    if (base >= n_elems) return;

    if (base + 4 <= n_elems) {
        // ---- coalesced element-stream loads (dwordx4 per lane) ----
        i32x4 c01 = __builtin_nontemporal_load((const i32x4*)(conn + 2 * base));
        i32x4 c23 = __builtin_nontemporal_load((const i32x4*)(conn + 2 * base + 4));
        f32x4 vE = __builtin_nontemporal_load((const f32x4*)(prop_E + base));
        f32x4 vA = __builtin_nontemporal_load((const f32x4*)(prop_A + base));
        f32x4 vI = __builtin_nontemporal_load((const f32x4*)(prop_I + base));

        int nA[4] = {c01.x, c01.z, c23.x, c23.z};
        int nB[4] = {c01.y, c01.w, c23.y, c23.w};

        // ---- issue ALL random gathers up front (16 independent loads) ----
        float cax[4], caz[4], cbx[4], cbz[4];
        float qA0[4], qA1[4], qA2[4], qB0[4], qB1[4], qB2[4];
        #pragma unroll
        for (int k = 0; k < 4; ++k) {
            const float* ca = coords + 3 * (long)nA[k];
            const float* cb = coords + 3 * (long)nB[k];
            const float* qa = pred   + 3 * (long)nA[k];
            const float* qb = pred   + 3 * (long)nB[k];
            cax[k] = ca[0]; caz[k] = ca[2];
            cbx[k] = cb[0]; cbz[k] = cb[2];
            qA0[k] = qa[0]; qA1[k] = qa[1]; qA2[k] = qa[2];
            qB0[k] = qb[0]; qB1[k] = qb[1]; qB2[k] = qb[2];
        }

        // ---- compute ----
        f32x4 oN, oM1, oM2, oV, oL, oC, oS;
        float fgA0[4], fgA1[4], fgA2[4], fgB0[4], fgB1[4], fgB2[4];

        #pragma unroll
        for (int k = 0; k < 4; ++k) {
            float dx0 = cbx[k] - cax[k];
            float dz0 = cbz[k] - caz[k];
            float l0 = sqrtf(dx0 * dx0 + dz0 * dz0);
            float c = dx0 / l0;
            float s = dz0 / l0;

            float E  = vE[k];
            float EA = E * vA[k];
            float EI = E * vI[k];

            float l0_2 = l0 * l0;
            float l0_3 = l0_2 * l0;
            float k_ax   = EA * u_c     / (F_c * l0);
            float k_bend = EI * theta_c / (M_c * l0);
            float k_sw   = EI * theta_c / (F_c * l0_2);
            float k_tr   = EI * u_c     / (F_c * l0_3);
            float k_mw   = EI * u_c     / (M_c * l0_2);

            float ua =  c * qA0[k] + s * qA1[k];
            float wa = -s * qA0[k] + c * qA1[k];
            float ta = -qA2[k];
            float ub =  c * qB0[k] + s * qB1[k];
            float wb = -s * qB0[k] + c * qB1[k];
            float tb = -qB2[k];

            float f0 = k_ax * (ua - ub);
            float f3 = k_ax * (ub - ua);
            float f1 = 12.0f * k_tr * (wa - wb) + 6.0f * k_sw * (ta + tb);
            float f4 = 12.0f * k_tr * (wb - wa) - 6.0f * k_sw * (ta + tb);
            float f2 = 6.0f * k_mw * (wa - wb) + k_bend * (4.0f * ta + 2.0f * tb);
            float f5 = 6.0f * k_mw * (wa - wb) + k_bend * (2.0f * ta + 4.0f * tb);

            oN[k]  = f3 * F_c;
            oM1[k] = f2 * M_c;
            oM2[k] = f5 * M_c;
            oV[k]  = f4 * F_c;
            oL[k]  = l0;
            oC[k]  = c;
            oS[k]  = s;

            fgA0[k] = c * f0 - s * f1;
            fgA1[k] = s * f0 + c * f1;
            fgA2[k] = f2;
            fgB0[k] = c * f3 - s * f4;
            fgB1[k] = s * f3 + c * f4;
            fgB2[k] = f5;
        }

        // ---- coalesced element-stream stores (nontemporal: pure streaming) ----
        __builtin_nontemporal_store(oN,  (f32x4*)(N_e  + base));
        __builtin_nontemporal_store(oM1, (f32x4*)(M1_e + base));
        __builtin_nontemporal_store(oM2, (f32x4*)(M2_e + base));
        __builtin_nontemporal_store(oV,  (f32x4*)(V_e  + base));
        __builtin_nontemporal_store(oL,  (f32x4*)(l0_o + base));
        __builtin_nontemporal_store(oC,  (f32x4*)(c_o  + base));
        __builtin_nontemporal_store(oS,  (f32x4*)(s_o  + base));

        // ---- nodal scatter ----
        #pragma unroll
        for (int k = 0; k < 4; ++k) {
            float* pa = nodal + 3 * (long)nA[k];
            float* pb = nodal + 3 * (long)nB[k];
            atomic_add_f32(pa + 0, fgA0[k]);
            atomic_add_f32(pa + 1, fgA1[k]);
            atomic_add_f32(pa + 2, fgA2[k]);
            atomic_add_f32(pb + 0, fgB0[k]);
            atomic_add_f32(pb + 1, fgB1[k]);
            atomic_add_f32(pb + 2, fgB2[k]);
        }
    } else {
        // tail: scalar path
        for (long e = base; e < n_elems; ++e) {
            int nA = conn[2 * e + 0];
            int nB = conn[2 * e + 1];
            float dx0 = coords[3 * nB + 0] - coords[3 * nA + 0];
            float dz0 = coords[3 * nB + 2] - coords[3 * nA + 2];
            float l0 = sqrtf(dx0 * dx0 + dz0 * dz0);
            float c = dx0 / l0;
            float s = dz0 / l0;
            float E  = prop_E[e];
            float EA = E * prop_A[e];
            float EI = E * prop_I[e];
            float l0_2 = l0 * l0;
            float l0_3 = l0_2 * l0;
            float k_ax   = EA * u_c     / (F_c * l0);
            float k_bend = EI * theta_c / (M_c * l0);
            float k_sw   = EI * theta_c / (F_c * l0_2);
            float k_tr   = EI * u_c     / (F_c * l0_3);
            float k_mw   = EI * u_c     / (M_c * l0_2);
            float pA0 = pred[3 * nA + 0], pA1 = pred[3 * nA + 1], pA2 = pred[3 * nA + 2];
            float pB0 = pred[3 * nB + 0], pB1 = pred[3 * nB + 1], pB2 = pred[3 * nB + 2];
            float ua =  c * pA0 + s * pA1;
            float wa = -s * pA0 + c * pA1;
            float ta = -pA2;
            float ub =  c * pB0 + s * pB1;
            float wb = -s * pB0 + c * pB1;
            float tb = -pB2;
            float f0 = k_ax * (ua - ub);
            float f3 = k_ax * (ub - ua);
            float f1 = 12.0f * k_tr * (wa - wb) + 6.0f * k_sw * (ta + tb);
            float f4 = 12.0f * k_tr * (wb - wa) - 6.0f * k_sw * (ta + tb);
            float f2 = 6.0f * k_mw * (wa - wb) + k_bend * (4.0f * ta + 2.0f * tb);
            float f5 = 6.0f * k_mw * (wa - wb) + k_bend * (2.0f * ta + 4.0f * tb);
            N_e[e]  = f3 * F_c;
            M1_e[e] = f2 * M_c;
            M2_e[e] = f5 * M_c;
            V_e[e]  = f4 * F_c;
            l0_o[e] = l0;
            c_o[e]  = c;
            s_o[e]  = s;
            atomic_add_f32(&nodal[3 * nA + 0], c * f0 - s * f1);
            atomic_add_f32(&nodal[3 * nA + 1], s * f0 + c * f1);
            atomic_add_f32(&nodal[3 * nA + 2], f2);
            atomic_add_f32(&nodal[3 * nB + 0], c * f3 - s * f4);
            atomic_add_f32(&nodal[3 * nB + 1], s * f3 + c * f4);
            atomic_add_f32(&nodal[3 * nB + 2], f5);
        }
    }
}

extern "C" void kernel_launch(void* const* d_in, const int* in_sizes, int n_in,
                              void* d_out, int out_size, void* d_ws, size_t ws_size,
                              hipStream_t stream) {
    const float* pred    = (const float*)d_in[0];
    const float* coords  = (const float*)d_in[1];
    const int*   conn    = (const int*)  d_in[2];
    const float* prop_E  = (const float*)d_in[3];
    const float* prop_A  = (const float*)d_in[4];
    const float* prop_I  = (const float*)d_in[5];
    const float* Fext    = (const float*)d_in[6];
    const float* u_c_p   = (const float*)d_in[7];
    const float* th_c_p  = (const float*)d_in[8];
    const float* F_c_p   = (const float*)d_in[9];
    const float* M_c_p   = (const float*)d_in[10];

    const int n3      = in_sizes[0];        // N_NODES*3
    const int n_elems = in_sizes[3];        // N_ELEMS

    float* out     = (float*)d_out;
    float* nodal   = out;
    float* Fext_nd = nodal + (size_t)n3;
    float* N_e     = Fext_nd + (size_t)n3;
    float* M1_e    = N_e + (size_t)n_elems;
    float* M2_e    = M1_e + (size_t)n_elems;
    float* V_e     = M2_e + (size_t)n_elems;
    float* phys    = V_e + (size_t)n_elems;
    float* l0_o    = phys + (size_t)n3;
    float* c_o     = l0_o + (size_t)n_elems;
    float* s_o     = c_o + (size_t)n_elems;

    const int BLK = 256;
    const int VPT = 4;

    int threads1 = (n3 + VPT - 1) / VPT;
    int grid1 = (threads1 + BLK - 1) / BLK;
    beam_node_kernel<<<grid1, BLK, 0, stream>>>(pred, Fext, u_c_p, th_c_p, F_c_p, M_c_p,
                                                nodal, Fext_nd, phys, n3);

    int threads2 = (n_elems + VPT - 1) / VPT;
    int grid2 = (threads2 + BLK - 1) / BLK;
    beam_elem_kernel<<<grid2, BLK, 0, stream>>>(pred, coords, conn, prop_E, prop_A, prop_I,
                                                u_c_p, th_c_p, F_c_p, M_c_p,
                                                nodal, N_e, M1_e, M2_e, V_e, l0_o, c_o, s_o,
                                                n_elems);
}